// Round 2
// baseline (5770.772 us; speedup 1.0000x reference)
//
#include <hip/hip_runtime.h>
#include <cmath>

#define BB 128
#define TT 256
#define DD 512
#define HH 256
#define G3 768   // 3*H

// ---------------- transpose w_hh (768,256) -> wT (256,768) ----------------
__global__ __launch_bounds__(256) void transpose_whh(
    const float* __restrict__ w_f, const float* __restrict__ w_b,
    float* __restrict__ wT_f, float* __restrict__ wT_b)
{
  const float* w = blockIdx.y ? w_b : w_f;
  float* wT = blockIdx.y ? wT_b : wT_f;
  int o = blockIdx.x * 256 + threadIdx.x;   // o = k*768 + j
  int k = o / G3, j = o - k * G3;
  wT[o] = w[j * HH + k];
}

// ---- GEMM: C[m,n] = bias[n] + sum_k A[m,k]*W[n,k]; A (M,K), W (N,K) ------
// 128x128 tile, BK=16, 256 threads, 8x8 micro as 2x2 of float4 quads.
// M%128==0, K%16==0 assumed; N guarded (used with N=768 and N=64).
__global__ __launch_bounds__(256) void gemm_abt(
    const float* __restrict__ A, const float* __restrict__ W,
    const float* __restrict__ bias, float* __restrict__ C,
    int M, int N, int K)
{
  __shared__ float sA[16][132];
  __shared__ float sB[16][132];
  const int tid = threadIdx.x;
  const int row0 = blockIdx.y * 128, col0 = blockIdx.x * 128;
  const int tx = tid & 15, ty = tid >> 4;
  float acc[8][8];
#pragma unroll
  for (int i = 0; i < 8; i++)
#pragma unroll
    for (int j = 0; j < 8; j++) acc[i][j] = 0.f;

  for (int k0 = 0; k0 < K; k0 += 16) {
    __syncthreads();
#pragma unroll
    for (int i = 0; i < 2; i++) {
      int q = tid + i * 256;
      int r = q >> 2, k4 = (q & 3) * 4;
      float4 av = *(const float4*)(A + (size_t)(row0 + r) * K + k0 + k4);
      sA[k4 + 0][r] = av.x; sA[k4 + 1][r] = av.y;
      sA[k4 + 2][r] = av.z; sA[k4 + 3][r] = av.w;
      float4 wv = make_float4(0.f, 0.f, 0.f, 0.f);
      if (col0 + r < N) wv = *(const float4*)(W + (size_t)(col0 + r) * K + k0 + k4);
      sB[k4 + 0][r] = wv.x; sB[k4 + 1][r] = wv.y;
      sB[k4 + 2][r] = wv.z; sB[k4 + 3][r] = wv.w;
    }
    __syncthreads();
#pragma unroll
    for (int k = 0; k < 16; k++) {
      float a0[8], b0[8];
      *(float4*)&a0[0] = *(const float4*)&sA[k][ty * 4];
      *(float4*)&a0[4] = *(const float4*)&sA[k][64 + ty * 4];
      *(float4*)&b0[0] = *(const float4*)&sB[k][tx * 4];
      *(float4*)&b0[4] = *(const float4*)&sB[k][64 + tx * 4];
#pragma unroll
      for (int i = 0; i < 8; i++)
#pragma unroll
        for (int j = 0; j < 8; j++) acc[i][j] += a0[i] * b0[j];
    }
  }
#pragma unroll
  for (int i = 0; i < 8; i++) {
    int r = row0 + ((i < 4) ? (ty * 4 + i) : (64 + ty * 4 + i - 4));
#pragma unroll
    for (int jq = 0; jq < 2; jq++) {
      int c = col0 + jq * 64 + tx * 4;
      if (c < N) {
        float4 v;
        v.x = acc[i][jq * 4 + 0] + bias[c + 0];
        v.y = acc[i][jq * 4 + 1] + bias[c + 1];
        v.z = acc[i][jq * 4 + 2] + bias[c + 2];
        v.w = acc[i][jq * 4 + 3] + bias[c + 3];
        *(float4*)(C + (size_t)r * N + c) = v;
      }
    }
  }
}

// ---------------- GRU recurrence, ONE direction per launch ----------------
// 1 block per batch-pair (64 blocks). thread j owns hidden unit j (gate rows
// j, H+j, 2H+j -> no cross-thread comm for the update). h (2 batches) in LDS.
// backward dir == iterate p = len-1..0 (input row == output row, no gather).
__global__ __launch_bounds__(256) void gru_dir_kernel(
    const float* __restrict__ xg, const float* __restrict__ wT,
    const float* __restrict__ bhh, const int* __restrict__ lengths,
    float* __restrict__ outp, int dir)
{
  const int j = threadIdx.x;
  const int b0 = blockIdx.x * 2, b1 = b0 + 1;
  const int len0 = lengths[b0], len1 = lengths[b1];
  const int tmax = len0 > len1 ? len0 : len1;
  __shared__ float2 h2[HH];
  h2[j] = make_float2(0.f, 0.f);
  __syncthreads();
  const float br = bhh[j], bz = bhh[HH + j], bn = bhh[2 * HH + j];
  for (int t = 0; t < tmax; t++) {
    const bool a0 = t < len0, a1 = t < len1;
    const int p0 = dir ? (len0 - 1 - t) : t;
    const int p1 = dir ? (len1 - 1 - t) : t;
    float xr0 = 0, xz0 = 0, xn0 = 0, xr1 = 0, xz1 = 0, xn1 = 0;
    if (a0) { const float* x = xg + ((size_t)b0 * TT + p0) * G3;
      xr0 = x[j]; xz0 = x[HH + j]; xn0 = x[2 * HH + j]; }
    if (a1) { const float* x = xg + ((size_t)b1 * TT + p1) * G3;
      xr1 = x[j]; xz1 = x[HH + j]; xn1 = x[2 * HH + j]; }
    float ar0 = 0, az0 = 0, an0 = 0, ar1 = 0, az1 = 0, an1 = 0;
#pragma unroll 8
    for (int k = 0; k < HH; k++) {
      float2 h = h2[k];
      float wr = wT[k * G3 + j];
      float wz = wT[k * G3 + HH + j];
      float wn = wT[k * G3 + 2 * HH + j];
      ar0 += h.x * wr; az0 += h.x * wz; an0 += h.x * wn;
      ar1 += h.y * wr; az1 += h.y * wz; an1 += h.y * wn;
    }
    float2 hold = h2[j];
    float h0n = hold.x, h1n = hold.y;
    if (a0) {
      float r = 1.f / (1.f + expf(-(xr0 + ar0 + br)));
      float z = 1.f / (1.f + expf(-(xz0 + az0 + bz)));
      float n = tanhf(xn0 + r * (an0 + bn));
      h0n = (1.f - z) * n + z * hold.x;
      outp[((size_t)b0 * TT + p0) * (2 * HH) + dir * HH + j] = h0n;
    }
    if (a1) {
      float r = 1.f / (1.f + expf(-(xr1 + ar1 + br)));
      float z = 1.f / (1.f + expf(-(xz1 + az1 + bz)));
      float n = tanhf(xn1 + r * (an1 + bn));
      h1n = (1.f - z) * n + z * hold.y;
      outp[((size_t)b1 * TT + p1) * (2 * HH) + dir * HH + j] = h1n;
    }
    __syncthreads();
    h2[j] = make_float2(h0n, h1n);
    __syncthreads();
  }
}

// ------------- scores from hmid: relu, dot w2, +b2; mask t>=len ----------
__global__ __launch_bounds__(256) void score2_kernel(
    const float* __restrict__ hmid, const float* __restrict__ w2,
    const float* __restrict__ b2, const int* __restrict__ lengths,
    float* __restrict__ scores)
{
  const int wv = threadIdx.x >> 6, lane = threadIdx.x & 63;
  const int bt = blockIdx.x * 4 + wv;
  const int b = bt >> 8, t = bt & 255;
  float v = 0.f;
  if (t < lengths[b]) {
    float hv = fmaxf(hmid[(size_t)bt * 64 + lane], 0.f);
    v = hv * w2[lane];
#pragma unroll
    for (int o = 32; o > 0; o >>= 1) v += __shfl_down(v, o);
    v += b2[0];
  }
  if (lane == 0) scores[bt] = v;
}

// -------- softmax + top-3 + normalize + seq_feat, 1 block per batch ------
__global__ __launch_bounds__(256) void attn_kernel(
    const float* __restrict__ scores, const float* __restrict__ outp,
    const float* __restrict__ temp_ptr, const int* __restrict__ lengths,
    float* __restrict__ seq_feat)
{
  const int b = blockIdx.x;
  const int t = threadIdx.x;
  const int len = lengths[b];
  float temp = fminf(fmaxf(temp_ptr[0], 0.001f), 10.0f);
  __shared__ float red[256];
  __shared__ int redi[256];
  __shared__ float topv[3]; __shared__ int topi[3];
  __shared__ float vn[3]; __shared__ float vsum_s;
  const bool valid = t < len;
  float logit = valid ? scores[b * TT + t] / temp : -INFINITY;
  red[t] = logit; __syncthreads();
  for (int s = 128; s > 0; s >>= 1) {
    if (t < s) red[t] = fmaxf(red[t], red[t + s]);
    __syncthreads();
  }
  float mx = red[0]; __syncthreads();
  float e = valid ? expf(logit - mx) : 0.f;
  red[t] = e; __syncthreads();
  for (int s = 128; s > 0; s >>= 1) {
    if (t < s) red[t] += red[t + s];
    __syncthreads();
  }
  float sum = red[0]; __syncthreads();
  float myp = e / sum;            // this thread's prob; ties -> lowest index
  for (int it = 0; it < 3; it++) {
    red[t] = myp; redi[t] = t; __syncthreads();
    for (int s = 128; s > 0; s >>= 1) {
      if (t < s) {
        float v2 = red[t + s]; int i2 = redi[t + s];
        if (v2 > red[t] || (v2 == red[t] && i2 < redi[t])) { red[t] = v2; redi[t] = i2; }
      }
      __syncthreads();
    }
    if (t == 0) { topv[it] = red[0]; topi[it] = redi[0]; }
    __syncthreads();
    if (t == topi[it]) myp = -1.f;   // exclude from next pass
    __syncthreads();
  }
  if (t == 0) {
    int k_act = len < 3 ? len : 3;
    float vsum = 0.f;
    for (int jj = 0; jj < 3; jj++) if (jj < k_act) vsum += topv[jj];
    vsum_s = vsum;
    float denom = fmaxf(vsum, 1e-8f);
    for (int jj = 0; jj < 3; jj++) vn[jj] = (jj < k_act) ? topv[jj] / denom : 0.f;
  }
  __syncthreads();
  if (vsum_s > 1e-8f) {
    for (int hh = t; hh < 2 * HH; hh += 256) {
      float s = 0.f;
      for (int jj = 0; jj < 3; jj++)
        s += vn[jj] * outp[((size_t)b * TT + topi[jj]) * (2 * HH) + hh];
      seq_feat[b * 2 * HH + hh] = s;
    }
  } else {  // uniform-over-valid fallback (never triggers in practice)
    float inv = 1.f / ((float)len + 1e-8f);
    for (int hh = t; hh < 2 * HH; hh += 256) {
      float s = 0.f;
      for (int tt2 = 0; tt2 < len; tt2++)
        s += outp[((size_t)b * TT + tt2) * (2 * HH) + hh];
      seq_feat[b * 2 * HH + hh] = s * inv;
    }
  }
}

// ------------------- final heads: (B,11) then (B,10) ---------------------
__global__ __launch_bounds__(256) void head_kernel(
    const float* __restrict__ seq_feat,
    const float* __restrict__ w_tens, const float* __restrict__ b_tens,
    const float* __restrict__ w_ones, const float* __restrict__ b_ones,
    float* __restrict__ d_out)
{
  const int b = blockIdx.x;
  const int lane = threadIdx.x & 63, wv = threadIdx.x >> 6;
  const float* sf = seq_feat + (size_t)b * 2 * HH;
  for (int o = wv; o < 21; o += 4) {
    const float* wr = (o < 11) ? (w_tens + (size_t)o * 2 * HH)
                               : (w_ones + (size_t)(o - 11) * 2 * HH);
    float s = 0.f;
    for (int e2 = lane; e2 < 2 * HH; e2 += 64) s += sf[e2] * wr[e2];
#pragma unroll
    for (int off2 = 32; off2 > 0; off2 >>= 1) s += __shfl_down(s, off2);
    if (lane == 0) {
      if (o < 11) d_out[b * 11 + o] = s + b_tens[o];
      else d_out[BB * 11 + b * 10 + (o - 11)] = s + b_ones[o - 11];
    }
  }
}

extern "C" void kernel_launch(void* const* d_in, const int* in_sizes, int n_in,
                              void* d_out, int out_size, void* d_ws, size_t ws_size,
                              hipStream_t stream)
{
  const float* feats       = (const float*)d_in[0];
  const int*   lengths     = (const int*)d_in[1];
  const float* temperature = (const float*)d_in[2];
  const float* w_ih_f = (const float*)d_in[3];
  const float* w_hh_f = (const float*)d_in[4];
  const float* b_ih_f = (const float*)d_in[5];
  const float* b_hh_f = (const float*)d_in[6];
  const float* w_ih_b = (const float*)d_in[7];
  const float* w_hh_b = (const float*)d_in[8];
  const float* b_ih_b = (const float*)d_in[9];
  const float* b_hh_b = (const float*)d_in[10];
  const float* w1 = (const float*)d_in[11];
  const float* b1 = (const float*)d_in[12];
  const float* w2 = (const float*)d_in[13];
  const float* b2 = (const float*)d_in[14];
  const float* w_tens = (const float*)d_in[15];
  const float* b_tens = (const float*)d_in[16];
  const float* w_ones = (const float*)d_in[17];
  const float* b_ones = (const float*)d_in[18];
  float* out = (float*)d_out;

  // ---- workspace layout (peak 169.4 MB; xg region reused 3 ways) ----
  char* ws = (char*)d_ws;
  size_t off = 0;
  auto alloc = [&](size_t nfloats) {
    float* p = (float*)(ws + off);
    off += nfloats * sizeof(float);
    return p;
  };
  float* xg   = alloc((size_t)BB * TT * G3);      // 100.7 MB, reused per dir
  float* outp = alloc((size_t)BB * TT * 2 * HH);  // 67.1 MB
  float* wT_f = alloc((size_t)HH * G3);           // 0.79 MB
  float* wT_b = alloc((size_t)HH * G3);           // 0.79 MB
  // after both GRU passes xg is dead -> alias the small tail buffers there
  float* hmid     = xg;                                   // 8.4 MB
  float* scores   = xg + (size_t)BB * TT * 64;            // 0.13 MB
  float* seq_feat = scores + (size_t)BB * TT;             // 0.26 MB

  transpose_whh<<<dim3(768, 2), 256, 0, stream>>>(w_hh_f, w_hh_b, wT_f, wT_b);
  // forward direction
  gemm_abt<<<dim3(6, 256), 256, 0, stream>>>(feats, w_ih_f, b_ih_f, xg, BB * TT, G3, DD);
  gru_dir_kernel<<<64, 256, 0, stream>>>(xg, wT_f, b_hh_f, lengths, outp, 0);
  // backward direction (reuses xg)
  gemm_abt<<<dim3(6, 256), 256, 0, stream>>>(feats, w_ih_b, b_ih_b, xg, BB * TT, G3, DD);
  gru_dir_kernel<<<64, 256, 0, stream>>>(xg, wT_b, b_hh_b, lengths, outp, 1);
  // score MLP + attention + heads
  gemm_abt<<<dim3(1, 256), 256, 0, stream>>>(outp, w1, b1, hmid, BB * TT, 64, 2 * HH);
  score2_kernel<<<BB * TT / 4, 256, 0, stream>>>(hmid, w2, b2, lengths, scores);
  attn_kernel<<<BB, 256, 0, stream>>>(scores, outp, temperature, lengths, seq_feat);
  head_kernel<<<BB, 256, 0, stream>>>(seq_feat, w_tens, b_tens, w_ones, b_ones, out);
}

// Round 3
// 4863.604 us; speedup vs baseline: 1.1865x; 1.1865x over previous
//
#include <hip/hip_runtime.h>
#include <cmath>

#define BB 128
#define TT 256
#define DD 512
#define HH 256
#define G3 768   // 3*H

// ---- GEMM: C[m,n] = bias[n] + sum_k A[m,k]*W[n,k]; A (M,K), W (N,K) ------
__global__ __launch_bounds__(256) void gemm_abt(
    const float* __restrict__ A, const float* __restrict__ W,
    const float* __restrict__ bias, float* __restrict__ C,
    int M, int N, int K)
{
  __shared__ float sA[16][132];
  __shared__ float sB[16][132];
  const int tid = threadIdx.x;
  const int row0 = blockIdx.y * 128, col0 = blockIdx.x * 128;
  const int tx = tid & 15, ty = tid >> 4;
  float acc[8][8];
#pragma unroll
  for (int i = 0; i < 8; i++)
#pragma unroll
    for (int j = 0; j < 8; j++) acc[i][j] = 0.f;

  for (int k0 = 0; k0 < K; k0 += 16) {
    __syncthreads();
#pragma unroll
    for (int i = 0; i < 2; i++) {
      int q = tid + i * 256;
      int r = q >> 2, k4 = (q & 3) * 4;
      float4 av = *(const float4*)(A + (size_t)(row0 + r) * K + k0 + k4);
      sA[k4 + 0][r] = av.x; sA[k4 + 1][r] = av.y;
      sA[k4 + 2][r] = av.z; sA[k4 + 3][r] = av.w;
      float4 wv = make_float4(0.f, 0.f, 0.f, 0.f);
      if (col0 + r < N) wv = *(const float4*)(W + (size_t)(col0 + r) * K + k0 + k4);
      sB[k4 + 0][r] = wv.x; sB[k4 + 1][r] = wv.y;
      sB[k4 + 2][r] = wv.z; sB[k4 + 3][r] = wv.w;
    }
    __syncthreads();
#pragma unroll
    for (int k = 0; k < 16; k++) {
      float a0[8], b0[8];
      *(float4*)&a0[0] = *(const float4*)&sA[k][ty * 4];
      *(float4*)&a0[4] = *(const float4*)&sA[k][64 + ty * 4];
      *(float4*)&b0[0] = *(const float4*)&sB[k][tx * 4];
      *(float4*)&b0[4] = *(const float4*)&sB[k][64 + tx * 4];
#pragma unroll
      for (int i = 0; i < 8; i++)
#pragma unroll
        for (int j = 0; j < 8; j++) acc[i][j] += a0[i] * b0[j];
    }
  }
#pragma unroll
  for (int i = 0; i < 8; i++) {
    int r = row0 + ((i < 4) ? (ty * 4 + i) : (64 + ty * 4 + i - 4));
#pragma unroll
    for (int jq = 0; jq < 2; jq++) {
      int c = col0 + jq * 64 + tx * 4;
      if (c < N) {
        float4 v;
        v.x = acc[i][jq * 4 + 0] + bias[c + 0];
        v.y = acc[i][jq * 4 + 1] + bias[c + 1];
        v.z = acc[i][jq * 4 + 2] + bias[c + 2];
        v.w = acc[i][jq * 4 + 3] + bias[c + 3];
        *(float4*)(C + (size_t)r * N + c) = v;
      }
    }
  }
}

// -------- weight-stationary GRU with per-group grid barrier --------------
// grid = 128 blocks = 16 unit-groups (16 units) x 8 batch-tiles (16 batches).
// w_hh slice (48 rows x 256) lives in LDS for the whole recurrence; h streams
// through a double-buffered global H with a monotonic-counter barrier per
// step, PER BATCH-TILE GROUP (16 blocks/counter; groups independent).
// Thread: jj = tid&127 -> (batch bb = jj>>3, unit-pair pp = jj&7),
//         kc = tid>>7 in [0,4): 64-wide k-slice; 4-way LDS reduction.
__global__ __launch_bounds__(512) void gru_sync_kernel(
    const float* __restrict__ xg, const float* __restrict__ w_hh,
    const float* __restrict__ bhh, const int* __restrict__ lengths,
    float* __restrict__ outp, float* __restrict__ Hbuf,  // [2][128][256]
    unsigned* __restrict__ cnt, int dir)
{
  const int tid = threadIdx.x;
  const int bt = blockIdx.x & 7, ug = blockIdx.x >> 3;
  const int b0g = bt * 16, u0 = ug * 16;
  unsigned* mycnt = cnt + bt * 16;   // 64 B apart

  __shared__ float w_s[3][16][268];   // 51.5 KB, padded stride vs conflicts
  __shared__ float h_s[16][268];      // 17.2 KB
  __shared__ float part[4][128][6];   // 12.3 KB
  __shared__ int len_s[16];

  // load weight slice (rows g*256+u0+uu of w_hh, row-major, coalesced)
  for (int idx = tid; idx < 3 * 16 * 64; idx += 512) {
    int kq = idx & 63, uu = (idx >> 6) & 15, g = idx >> 10;
    float4 v = *(const float4*)(w_hh + (size_t)(g * 256 + u0 + uu) * 256 + kq * 4);
    w_s[g][uu][kq * 4 + 0] = v.x; w_s[g][uu][kq * 4 + 1] = v.y;
    w_s[g][uu][kq * 4 + 2] = v.z; w_s[g][uu][kq * 4 + 3] = v.w;
  }
  if (tid < 16) len_s[tid] = lengths[b0g + tid];
  // zero our slice of H[0]
  if (tid < 256) Hbuf[(size_t)(b0g + (tid >> 4)) * 256 + u0 + (tid & 15)] = 0.f;
  __syncthreads();
  int tmax = 0;
#pragma unroll
  for (int i = 0; i < 16; i++) tmax = max(tmax, len_s[i]);  // uniform in group

  unsigned bar = 1;
  if (tid == 0) {
    __hip_atomic_fetch_add(mycnt, 1u, __ATOMIC_RELEASE, __HIP_MEMORY_SCOPE_AGENT);
    while (__hip_atomic_load(mycnt, __ATOMIC_ACQUIRE, __HIP_MEMORY_SCOPE_AGENT) < 16u * bar)
      __builtin_amdgcn_s_sleep(2);
  }
  __syncthreads();

  const int jj = tid & 127, kc = tid >> 7;
  const int bb = jj >> 3, pp = jj & 7;
  const int up0 = 2 * pp, up1 = 2 * pp + 1;
  const int u_a = u0 + up0;                 // even
  const int mylen = len_s[bb];
  const int k0 = kc * 64;
  // biases for my 2 units (used by reduce threads only)
  float br_a = bhh[u_a],       br_b = bhh[u_a + 1];
  float bz_a = bhh[HH + u_a],  bz_b = bhh[HH + u_a + 1];
  float bn_a = bhh[2*HH + u_a], bn_b = bhh[2*HH + u_a + 1];

  for (int t = 0; t < tmax; t++) {
    // stage H[read] -> h_s (16 KB, coalesced)
    {
      const float* Hr = Hbuf + (size_t)(t & 1) * BB * HH;
      int b = tid >> 5, c = (tid & 31) * 8;
      float4 v0 = *(const float4*)(Hr + (size_t)(b0g + b) * HH + c);
      float4 v1 = *(const float4*)(Hr + (size_t)(b0g + b) * HH + c + 4);
      *(float4*)&h_s[b][c] = v0;
      *(float4*)&h_s[b][c + 4] = v1;
    }
    // xg prefetch (reduce threads), overlapped with the k-loop
    const int active = (t < mylen);
    const int p = dir ? (mylen - 1 - t) : t;
    float2 xr2 = make_float2(0.f, 0.f), xz2 = xr2, xn2 = xr2;
    if (kc == 0 && active) {
      const float* x = xg + ((size_t)(b0g + bb) * TT + p) * G3;
      xr2 = *(const float2*)(x + u_a);
      xz2 = *(const float2*)(x + HH + u_a);
      xn2 = *(const float2*)(x + 2 * HH + u_a);
    }
    __syncthreads();

    float a0 = 0.f, a1 = 0.f, a2 = 0.f, a3 = 0.f, a4 = 0.f, a5 = 0.f;
#pragma unroll 4
    for (int k = k0; k < k0 + 64; k += 4) {
      float4 h4  = *(const float4*)&h_s[bb][k];
      float4 wra = *(const float4*)&w_s[0][up0][k];
      float4 wrb = *(const float4*)&w_s[0][up1][k];
      float4 wza = *(const float4*)&w_s[1][up0][k];
      float4 wzb = *(const float4*)&w_s[1][up1][k];
      float4 wna = *(const float4*)&w_s[2][up0][k];
      float4 wnb = *(const float4*)&w_s[2][up1][k];
      a0 += h4.x*wra.x + h4.y*wra.y + h4.z*wra.z + h4.w*wra.w;
      a1 += h4.x*wza.x + h4.y*wza.y + h4.z*wza.z + h4.w*wza.w;
      a2 += h4.x*wna.x + h4.y*wna.y + h4.z*wna.z + h4.w*wna.w;
      a3 += h4.x*wrb.x + h4.y*wrb.y + h4.z*wrb.z + h4.w*wrb.w;
      a4 += h4.x*wzb.x + h4.y*wzb.y + h4.z*wzb.z + h4.w*wzb.w;
      a5 += h4.x*wnb.x + h4.y*wnb.y + h4.z*wnb.z + h4.w*wnb.w;
    }
    if (kc != 0) {
      part[kc][jj][0] = a0; part[kc][jj][1] = a1; part[kc][jj][2] = a2;
      part[kc][jj][3] = a3; part[kc][jj][4] = a4; part[kc][jj][5] = a5;
    }
    __syncthreads();
    if (kc == 0) {
      float sr_a = a0 + part[1][jj][0] + part[2][jj][0] + part[3][jj][0];
      float sz_a = a1 + part[1][jj][1] + part[2][jj][1] + part[3][jj][1];
      float sn_a = a2 + part[1][jj][2] + part[2][jj][2] + part[3][jj][2];
      float sr_b = a3 + part[1][jj][3] + part[2][jj][3] + part[3][jj][3];
      float sz_b = a4 + part[1][jj][4] + part[2][jj][4] + part[3][jj][4];
      float sn_b = a5 + part[1][jj][5] + part[2][jj][5] + part[3][jj][5];
      if (active) {
        float hoa = h_s[bb][u_a], hob = h_s[bb][u_a + 1];
        float r0 = 1.f / (1.f + expf(-(xr2.x + sr_a + br_a)));
        float z0 = 1.f / (1.f + expf(-(xz2.x + sz_a + bz_a)));
        float n0 = tanhf(xn2.x + r0 * (sn_a + bn_a));
        float hna = (1.f - z0) * n0 + z0 * hoa;
        float r1 = 1.f / (1.f + expf(-(xr2.y + sr_b + br_b)));
        float z1 = 1.f / (1.f + expf(-(xz2.y + sz_b + bz_b)));
        float n1 = tanhf(xn2.y + r1 * (sn_b + bn_b));
        float hnb = (1.f - z1) * n1 + z1 * hob;
        float* Hw = Hbuf + (size_t)((t + 1) & 1) * BB * HH;
        *(float2*)(Hw + (size_t)(b0g + bb) * HH + u_a) = make_float2(hna, hnb);
        *(float2*)(outp + ((size_t)(b0g + bb) * TT + p) * (2 * HH) + dir * HH + u_a)
            = make_float2(hna, hnb);
      }
    }
    __syncthreads();          // all global H writes issued+drained per-thread
    bar++;
    if (tid == 0) {
      __hip_atomic_fetch_add(mycnt, 1u, __ATOMIC_RELEASE, __HIP_MEMORY_SCOPE_AGENT);
      while (__hip_atomic_load(mycnt, __ATOMIC_ACQUIRE, __HIP_MEMORY_SCOPE_AGENT) < 16u * bar)
        __builtin_amdgcn_s_sleep(2);
    }
    __syncthreads();
  }
}

// ------------- scores from hmid: relu, dot w2, +b2; mask t>=len ----------
__global__ __launch_bounds__(256) void score2_kernel(
    const float* __restrict__ hmid, const float* __restrict__ w2,
    const float* __restrict__ b2, const int* __restrict__ lengths,
    float* __restrict__ scores)
{
  const int wv = threadIdx.x >> 6, lane = threadIdx.x & 63;
  const int bt = blockIdx.x * 4 + wv;
  const int b = bt >> 8, t = bt & 255;
  float v = 0.f;
  if (t < lengths[b]) {
    float hv = fmaxf(hmid[(size_t)bt * 64 + lane], 0.f);
    v = hv * w2[lane];
#pragma unroll
    for (int o = 32; o > 0; o >>= 1) v += __shfl_down(v, o);
    v += b2[0];
  }
  if (lane == 0) scores[bt] = v;
}

// -------- softmax + top-3 + normalize + seq_feat, 1 block per batch ------
__global__ __launch_bounds__(256) void attn_kernel(
    const float* __restrict__ scores, const float* __restrict__ outp,
    const float* __restrict__ temp_ptr, const int* __restrict__ lengths,
    float* __restrict__ seq_feat)
{
  const int b = blockIdx.x;
  const int t = threadIdx.x;
  const int len = lengths[b];
  float temp = fminf(fmaxf(temp_ptr[0], 0.001f), 10.0f);
  __shared__ float red[256];
  __shared__ int redi[256];
  __shared__ float topv[3]; __shared__ int topi[3];
  __shared__ float vn[3]; __shared__ float vsum_s;
  const bool valid = t < len;
  float logit = valid ? scores[b * TT + t] / temp : -INFINITY;
  red[t] = logit; __syncthreads();
  for (int s = 128; s > 0; s >>= 1) {
    if (t < s) red[t] = fmaxf(red[t], red[t + s]);
    __syncthreads();
  }
  float mx = red[0]; __syncthreads();
  float e = valid ? expf(logit - mx) : 0.f;
  red[t] = e; __syncthreads();
  for (int s = 128; s > 0; s >>= 1) {
    if (t < s) red[t] += red[t + s];
    __syncthreads();
  }
  float sum = red[0]; __syncthreads();
  float myp = e / sum;
  for (int it = 0; it < 3; it++) {
    red[t] = myp; redi[t] = t; __syncthreads();
    for (int s = 128; s > 0; s >>= 1) {
      if (t < s) {
        float v2 = red[t + s]; int i2 = redi[t + s];
        if (v2 > red[t] || (v2 == red[t] && i2 < redi[t])) { red[t] = v2; redi[t] = i2; }
      }
      __syncthreads();
    }
    if (t == 0) { topv[it] = red[0]; topi[it] = redi[0]; }
    __syncthreads();
    if (t == topi[it]) myp = -1.f;
    __syncthreads();
  }
  if (t == 0) {
    int k_act = len < 3 ? len : 3;
    float vsum = 0.f;
    for (int jj = 0; jj < 3; jj++) if (jj < k_act) vsum += topv[jj];
    vsum_s = vsum;
    float denom = fmaxf(vsum, 1e-8f);
    for (int jj = 0; jj < 3; jj++) vn[jj] = (jj < k_act) ? topv[jj] / denom : 0.f;
  }
  __syncthreads();
  if (vsum_s > 1e-8f) {
    for (int hh = t; hh < 2 * HH; hh += 256) {
      float s = 0.f;
      for (int jj = 0; jj < 3; jj++)
        s += vn[jj] * outp[((size_t)b * TT + topi[jj]) * (2 * HH) + hh];
      seq_feat[b * 2 * HH + hh] = s;
    }
  } else {
    float inv = 1.f / ((float)len + 1e-8f);
    for (int hh = t; hh < 2 * HH; hh += 256) {
      float s = 0.f;
      for (int tt2 = 0; tt2 < len; tt2++)
        s += outp[((size_t)b * TT + tt2) * (2 * HH) + hh];
      seq_feat[b * 2 * HH + hh] = s * inv;
    }
  }
}

// ------------------- final heads: (B,11) then (B,10) ---------------------
__global__ __launch_bounds__(256) void head_kernel(
    const float* __restrict__ seq_feat,
    const float* __restrict__ w_tens, const float* __restrict__ b_tens,
    const float* __restrict__ w_ones, const float* __restrict__ b_ones,
    float* __restrict__ d_out)
{
  const int b = blockIdx.x;
  const int lane = threadIdx.x & 63, wv = threadIdx.x >> 6;
  const float* sf = seq_feat + (size_t)b * 2 * HH;
  for (int o = wv; o < 21; o += 4) {
    const float* wr = (o < 11) ? (w_tens + (size_t)o * 2 * HH)
                               : (w_ones + (size_t)(o - 11) * 2 * HH);
    float s = 0.f;
    for (int e2 = lane; e2 < 2 * HH; e2 += 64) s += sf[e2] * wr[e2];
#pragma unroll
    for (int off2 = 32; off2 > 0; off2 >>= 1) s += __shfl_down(s, off2);
    if (lane == 0) {
      if (o < 11) d_out[b * 11 + o] = s + b_tens[o];
      else d_out[BB * 11 + b * 10 + (o - 11)] = s + b_ones[o - 11];
    }
  }
}

extern "C" void kernel_launch(void* const* d_in, const int* in_sizes, int n_in,
                              void* d_out, int out_size, void* d_ws, size_t ws_size,
                              hipStream_t stream)
{
  const float* feats       = (const float*)d_in[0];
  const int*   lengths     = (const int*)d_in[1];
  const float* temperature = (const float*)d_in[2];
  const float* w_ih_f = (const float*)d_in[3];
  const float* w_hh_f = (const float*)d_in[4];
  const float* b_ih_f = (const float*)d_in[5];
  const float* b_hh_f = (const float*)d_in[6];
  const float* w_ih_b = (const float*)d_in[7];
  const float* w_hh_b = (const float*)d_in[8];
  const float* b_ih_b = (const float*)d_in[9];
  const float* b_hh_b = (const float*)d_in[10];
  const float* w1 = (const float*)d_in[11];
  const float* b1 = (const float*)d_in[12];
  const float* w2 = (const float*)d_in[13];
  const float* b2 = (const float*)d_in[14];
  const float* w_tens = (const float*)d_in[15];
  const float* b_tens = (const float*)d_in[16];
  const float* w_ones = (const float*)d_in[17];
  const float* b_ones = (const float*)d_in[18];
  float* out = (float*)d_out;

  // ---- workspace layout (peak ~168 MB; xg reused per dir, tail aliased) --
  char* ws = (char*)d_ws;
  size_t off = 0;
  auto alloc = [&](size_t nfloats) {
    float* p = (float*)(ws + off);
    off += nfloats * sizeof(float);
    return p;
  };
  float*    xg    = alloc((size_t)BB * TT * G3);      // 100.7 MB
  float*    outp  = alloc((size_t)BB * TT * 2 * HH);  // 67.1 MB
  float*    Hbuf  = alloc((size_t)2 * BB * HH);       // 256 KB
  unsigned* cnt   = (unsigned*)(ws + off); off += 1024; // 8 counters x 64 B
  float* hmid     = xg;                               // aliases (xg dead)
  float* scores   = xg + (size_t)BB * TT * 64;
  float* seq_feat = scores + (size_t)BB * TT;

  hipMemsetAsync(cnt, 0, 1024, stream);
  // forward direction
  gemm_abt<<<dim3(6, 256), 256, 0, stream>>>(feats, w_ih_f, b_ih_f, xg, BB * TT, G3, DD);
  gru_sync_kernel<<<128, 512, 0, stream>>>(xg, w_hh_f, b_hh_f, lengths, outp, Hbuf, cnt, 0);
  // backward direction (reuses xg; fresh counters)
  hipMemsetAsync(cnt, 0, 1024, stream);
  gemm_abt<<<dim3(6, 256), 256, 0, stream>>>(feats, w_ih_b, b_ih_b, xg, BB * TT, G3, DD);
  gru_sync_kernel<<<128, 512, 0, stream>>>(xg, w_hh_b, b_hh_b, lengths, outp, Hbuf, cnt, 1);
  // score MLP + attention + heads
  gemm_abt<<<dim3(1, 256), 256, 0, stream>>>(outp, w1, b1, hmid, BB * TT, 64, 2 * HH);
  score2_kernel<<<BB * TT / 4, 256, 0, stream>>>(hmid, w2, b2, lengths, scores);
  attn_kernel<<<BB, 256, 0, stream>>>(scores, outp, temperature, lengths, seq_feat);
  head_kernel<<<BB, 256, 0, stream>>>(seq_feat, w_tens, b_tens, w_ones, b_ones, out);
}